// Round 4
// baseline (155.800 us; speedup 1.0000x reference)
//
#include <hip/hip_runtime.h>

// SpatialDistangleLoss: loss = sum_p |y_p| * (box5x5(|y|)_p - |y_p|) / 25 / (H*W*B)
// y shape (8, 320, 96, 96) fp32 -> 2560 planes of 96x96.
//
// R4: direct-global rolling separable box (R1 structure — proven exact) with the
// atomic chain replaced by per-block partials + tiny finish kernel (R3 fix).
// R1's 62.8us was the 1440-deep same-address atomicAdd chain (~44ns each), not
// load latency; the overlapping float4 reads are L1/L2-served (plane = 36KB).
// Harness restore/poison adds a fixed ~100us outside our control.

#define HH 96
#define WW 96
#define NPLANES 2560          // 8 * 320
#define STRIP_H 16
#define GXN 24                // 24 groups of 4 columns = 96
#define STRIPS (HH / STRIP_H) // 6
#define TPP (GXN * STRIPS)    // 144 threads per plane
#define TOTAL (TPP * NPLANES) // 368640 = 1440 * 256
#define NBLOCKS (TOTAL / 256) // 1440
#define SCALE (1.0f / (25.0f * 96.0f * 96.0f * 8.0f))

__global__ __launch_bounds__(256) void sdl_partial(const float* __restrict__ y,
                                                   float* __restrict__ ws) {
    const int t = blockIdx.x * 256 + threadIdx.x;

    const int gx    = t % GXN;
    const int rest  = t / GXN;
    const int strip = rest % STRIPS;
    const int plane = rest / STRIPS;

    const float* base = y + (size_t)plane * (HH * WW);
    const int wbase = gx * 4;
    const int h0 = strip * STRIP_H;
    const bool has_left  = (wbase >= 4);
    const bool has_right = (wbase <= WW - 8);

    float rs[5][4];  // ring: horizontal 5-sums of |y| for the last 5 loaded rows
    float av[3][4];  // ring: center |y| values for the last 3 loaded rows
#pragma unroll
    for (int k = 0; k < 5; ++k)
#pragma unroll
        for (int j = 0; j < 4; ++j) rs[k][j] = 0.0f;
#pragma unroll
    for (int k = 0; k < 3; ++k)
#pragma unroll
        for (int j = 0; j < 4; ++j) av[k][j] = 0.0f;

    float acc = 0.0f;

#pragma unroll
    for (int i = 0; i < STRIP_H + 4; ++i) {
        const int r = h0 - 2 + i;  // row being loaded
        float x[12];               // cols wbase-4 .. wbase+7, |.| applied
        if ((unsigned)r < (unsigned)HH) {
            const float* rowp = base + r * WW + wbase;
            float4 m = *(const float4*)(rowp);
            float4 l = has_left  ? *(const float4*)(rowp - 4) : make_float4(0, 0, 0, 0);
            float4 rr = has_right ? *(const float4*)(rowp + 4) : make_float4(0, 0, 0, 0);
            x[0] = l.x;  x[1] = l.y;  x[2]  = l.z;  x[3]  = l.w;
            x[4] = m.x;  x[5] = m.y;  x[6]  = m.z;  x[7]  = m.w;
            x[8] = rr.x; x[9] = rr.y; x[10] = rr.z; x[11] = rr.w;
#pragma unroll
            for (int k = 0; k < 12; ++k) x[k] = fabsf(x[k]);
        } else {
#pragma unroll
            for (int k = 0; k < 12; ++k) x[k] = 0.0f;
        }

#pragma unroll
        for (int j = 0; j < 4; ++j) {
            rs[i % 5][j] = x[j + 2] + x[j + 3] + x[j + 4] + x[j + 5] + x[j + 6];
            av[i % 3][j] = x[j + 4];
        }

        if (i >= 4) {
#pragma unroll
            for (int j = 0; j < 4; ++j) {
                float box = rs[0][j] + rs[1][j] + rs[2][j] + rs[3][j] + rs[4][j];
                float a = av[(i - 2) % 3][j];
                acc += a * (box - a);
            }
        }
    }

    // ---- block reduction -> plain store of partial (NO atomics) ----
#pragma unroll
    for (int off = 32; off > 0; off >>= 1) acc += __shfl_down(acc, off, 64);

    __shared__ float red[4];
    const int lane = threadIdx.x & 63;
    const int wid  = threadIdx.x >> 6;
    if (lane == 0) red[wid] = acc;
    __syncthreads();
    if (threadIdx.x == 0) {
        ws[blockIdx.x] = red[0] + red[1] + red[2] + red[3];
    }
}

__global__ __launch_bounds__(256) void sdl_finish(const float* __restrict__ ws,
                                                  float* __restrict__ out) {
    const int tid = threadIdx.x;
    float acc = 0.0f;
#pragma unroll
    for (int k = 0; k < 6; ++k) {
        const int idx = tid + 256 * k;
        if (idx < NBLOCKS) acc += ws[idx];
    }
#pragma unroll
    for (int off = 32; off > 0; off >>= 1) acc += __shfl_down(acc, off, 64);
    __shared__ float red[4];
    const int lane = tid & 63;
    const int wid  = tid >> 6;
    if (lane == 0) red[wid] = acc;
    __syncthreads();
    if (tid == 0) {
        out[0] = (red[0] + red[1] + red[2] + red[3]) * SCALE;
    }
}

extern "C" void kernel_launch(void* const* d_in, const int* in_sizes, int n_in,
                              void* d_out, int out_size, void* d_ws, size_t ws_size,
                              hipStream_t stream) {
    const float* y = (const float*)d_in[0];
    float* ws = (float*)d_ws;
    float* out = (float*)d_out;
    sdl_partial<<<NBLOCKS, 256, 0, stream>>>(y, ws);
    sdl_finish<<<1, 256, 0, stream>>>(ws, out);
}

// Round 5
// 137.509 us; speedup vs baseline: 1.1330x; 1.1330x over previous
//
#include <hip/hip_runtime.h>

// SpatialDistangleLoss: loss = sum_p |y_p| * (box5x5(|y|)_p - |y_p|) / 25 / (H*W*B)
// y shape (8, 320, 96, 96) fp32 -> 2560 planes of 96x96.
//
// R5: quarter-plane LDS tiles. Staging is a pure streaming-copy pattern
// (independent coalesced float4 loads -> max MLP, like the 6.6TB/s fill kernels);
// compute is the separable 5x5 box from LDS. 11.2KB LDS -> many blocks/CU,
// 10240 blocks -> deep block queue hides cold-HBM latency (ws poison sweeps L3
// every launch, so input is always a cold fetch). No atomics (R2 showed a
// same-address atomic chain costs ~40ns/block serialized).

#define HH 96
#define WW 96
#define NPLANES 2560
#define QROWS 24                 // output rows per block
#define TROWS (QROWS + 4)        // staged rows incl. 2+2 halo
#define LSTRIDE 100              // floats; %4==0 for aligned float4, %32!=0 spreads banks
#define NBLOCKS (NPLANES * 4)    // 10240
#define NSTG ((TROWS * WW) / 4)  // 672 float4 stage loads per block
#define SCALE (1.0f / (25.0f * 96.0f * 96.0f * 8.0f))

__global__ __launch_bounds__(256) void sdl_partial(const float* __restrict__ y,
                                                   float* __restrict__ ws) {
    __shared__ float s[TROWS * LSTRIDE];  // 11200 B
    __shared__ float red[4];

    const int tid   = threadIdx.x;
    const int plane = blockIdx.x >> 2;
    const int q     = blockIdx.x & 3;
    const int row0  = q * QROWS;  // first output row
    const float* base = y + (size_t)plane * (HH * WW);

    // ---- stage 28 rows (row0-2 .. row0+25, zero-filled outside) as |y| ----
#pragma unroll
    for (int k = 0; k < 3; ++k) {
        const int idx = tid + 256 * k;  // 0..671
        if (idx < NSTG) {
            const int rl = idx / 24;   // local row 0..27
            const int c4 = idx % 24;
            const int gr = row0 - 2 + rl;
            float4 v = make_float4(0, 0, 0, 0);
            if ((unsigned)gr < (unsigned)HH)
                v = *(const float4*)(base + gr * WW + c4 * 4);
            float* d = &s[rl * LSTRIDE + c4 * 4];
            d[0] = fabsf(v.x);
            d[1] = fabsf(v.y);
            d[2] = fabsf(v.z);
            d[3] = fabsf(v.w);
        }
    }
    __syncthreads();

    // ---- compute from LDS: 192 threads = 24 col-groups x 8 row-strips(3 rows) ----
    float acc = 0.0f;
    if (tid < 192) {
        const int gx = tid % 24;
        const int rs = tid / 24;       // 0..7 -> output local rows rs*3 .. rs*3+2
        const bool hl = (gx >= 1);
        const bool hr = (gx <= 22);
        const int l0 = rs * 3;         // first LDS row this thread touches

        float rsum[5][4];
        float av[3][4];
#pragma unroll
        for (int k = 0; k < 5; ++k)
#pragma unroll
            for (int j = 0; j < 4; ++j) rsum[k][j] = 0.0f;
#pragma unroll
        for (int k = 0; k < 3; ++k)
#pragma unroll
            for (int j = 0; j < 4; ++j) av[k][j] = 0.0f;

#pragma unroll
        for (int i = 0; i < 7; ++i) {
            const float* rowp = &s[(l0 + i) * LSTRIDE + gx * 4];
            float4 m = *(const float4*)(rowp);
            float4 l = hl ? *(const float4*)(rowp - 4) : make_float4(0, 0, 0, 0);
            float4 r = hr ? *(const float4*)(rowp + 4) : make_float4(0, 0, 0, 0);
            float x[12];
            x[0] = l.x; x[1] = l.y; x[2]  = l.z; x[3]  = l.w;
            x[4] = m.x; x[5] = m.y; x[6]  = m.z; x[7]  = m.w;
            x[8] = r.x; x[9] = r.y; x[10] = r.z; x[11] = r.w;

#pragma unroll
            for (int j = 0; j < 4; ++j) {
                rsum[i % 5][j] = x[j + 2] + x[j + 3] + x[j + 4] + x[j + 5] + x[j + 6];
                av[i % 3][j] = x[j + 4];
            }

            if (i >= 4) {
#pragma unroll
                for (int j = 0; j < 4; ++j) {
                    float box = rsum[0][j] + rsum[1][j] + rsum[2][j] + rsum[3][j] + rsum[4][j];
                    float a = av[(i - 2) % 3][j];
                    acc += a * (box - a);
                }
            }
        }
    }

    // ---- block reduction -> plain store (NO atomics) ----
#pragma unroll
    for (int off = 32; off > 0; off >>= 1) acc += __shfl_down(acc, off, 64);
    const int lane = tid & 63;
    const int wid  = tid >> 6;
    if (lane == 0) red[wid] = acc;
    __syncthreads();
    if (tid == 0) {
        ws[blockIdx.x] = red[0] + red[1] + red[2] + red[3];
    }
}

__global__ __launch_bounds__(256) void sdl_finish(const float* __restrict__ ws,
                                                  float* __restrict__ out) {
    const int tid = threadIdx.x;
    float acc = 0.0f;
#pragma unroll
    for (int k = 0; k < NBLOCKS / 256; ++k) acc += ws[tid + 256 * k];
#pragma unroll
    for (int off = 32; off > 0; off >>= 1) acc += __shfl_down(acc, off, 64);
    __shared__ float red[4];
    const int lane = tid & 63;
    const int wid  = tid >> 6;
    if (lane == 0) red[wid] = acc;
    __syncthreads();
    if (tid == 0) {
        out[0] = (red[0] + red[1] + red[2] + red[3]) * SCALE;
    }
}

extern "C" void kernel_launch(void* const* d_in, const int* in_sizes, int n_in,
                              void* d_out, int out_size, void* d_ws, size_t ws_size,
                              hipStream_t stream) {
    const float* y = (const float*)d_in[0];
    float* ws = (float*)d_ws;
    float* out = (float*)d_out;
    sdl_partial<<<NBLOCKS, 256, 0, stream>>>(y, ws);
    sdl_finish<<<1, 256, 0, stream>>>(ws, out);
}